// Round 12
// baseline (204.147 us; speedup 1.0000x reference)
//
#include <hip/hip_runtime.h>
#include <math.h>

// ---------------------------------------------------------------------------
// RWKV7-ish CausalSelfAttention, MI355X gfx950.
// B=4 T=2048 C=1024 NH=16 HS=64.
// Pipeline: castall v2 (ILP-4) -> bf16 ;
//   GEMM1: proven 4-wave 256x128 core (128x64 wave tiles, BK=64, GLL16 +
//          swizzled LDS, 2-barrier, XCD swizzle) + fused groupnorm/erf -> E ;
//   band_vt rolling chunked scan -> vt ;
//   GEMM2 v4: K-split (R11) + SYMMETRIC-EXCHANGE epilogue: wk=0 deposits
//          rows 64..127 partial, wk=1 deposits rows 0..63; each wave reduces
//          and writes its own 64-row half -> all 256 threads stream the fp32
//          residual+output (2x store parallelism). Out stores nontemporal.
// Ceiling ledger: gemm1 = 67us is register-capped (212 regs/wave -> 2
//   waves/SIMD) at the proven 2-barrier structure; 4 schedule rewrites and
//   2 occupancy pushes all regressed or were null. Fill (768 tiles / 512
//   slots = 1.5 rounds) is invariant for any 128x64-per-wave tiling.
// Workspace: xb 16MB | Wab 6MB | Wpb 2MB | E 48MB | vt 16MB = 88MiB
// ---------------------------------------------------------------------------

typedef __attribute__((ext_vector_type(8))) short short8;     // 8 x bf16 bits
typedef __attribute__((ext_vector_type(4))) float floatx4;

#define GLL16(g, l)                                                            \
    __builtin_amdgcn_global_load_lds(                                          \
        (const __attribute__((address_space(1))) void*)(g),                    \
        (__attribute__((address_space(3))) void*)(l), 16, 0, 0)

static __device__ __forceinline__ unsigned short f2bf(float f) {
    unsigned u = __float_as_uint(f);
    unsigned r = (u + 0x7fffu + ((u >> 16) & 1u)) >> 16;
    return (unsigned short)r;
}
static __device__ __forceinline__ float bflo(unsigned v) { return __uint_as_float(v << 16); }

// Abramowitz-Stegun 7.1.28: |err| <= 3e-7, branch-free.
static __device__ __forceinline__ float erf_fast(float x) {
    float ax = __builtin_fabsf(x);
    float p = fmaf(0.0000430638f, ax, 0.0002765672f);
    p = fmaf(p, ax, 0.0001520143f);
    p = fmaf(p, ax, 0.0092705272f);
    p = fmaf(p, ax, 0.0422820123f);
    p = fmaf(p, ax, 0.0705230784f);
    p = fmaf(p, ax, 1.0f);
    float r = 1.0f / p;
    float r2 = r * r, r4 = r2 * r2, r8 = r4 * r4, r16 = r8 * r8;
    return __builtin_copysignf(1.0f - r16, x);
}

// sum across the 16 lanes of a DPP row, result in every lane of the row.
static __device__ __forceinline__ float sum16(float x) {
    int t;
    t = __builtin_amdgcn_update_dpp(0, __float_as_int(x), 0x128, 0xf, 0xf, false); // row_ror:8
    x += __int_as_float(t);
    t = __builtin_amdgcn_update_dpp(0, __float_as_int(x), 0x124, 0xf, 0xf, false); // row_ror:4
    x += __int_as_float(t);
    t = __builtin_amdgcn_update_dpp(0, __float_as_int(x), 0x122, 0xf, 0xf, false); // row_ror:2
    x += __int_as_float(t);
    t = __builtin_amdgcn_update_dpp(0, __float_as_int(x), 0x121, 0xf, 0xf, false); // row_ror:1
    x += __int_as_float(t);
    return x;
}
// full 64-lane sum, result in every lane.
static __device__ __forceinline__ float sum64_all(float x) {
    x = sum16(x);
    int t = __builtin_amdgcn_ds_swizzle(__float_as_int(x), 0x401F);  // xor 16 (within 32)
    x += __int_as_float(t);
    x += __shfl_xor(x, 32, 64);                                      // xor 32
    return x;
}

// ---------------- fused cast fp32 -> bf16 (x | Wa | Wp, contiguous out) -----
__global__ __launch_bounds__(256) void castall(const float4* __restrict__ x,
                                               const float4* __restrict__ wa,
                                               const float4* __restrict__ wp,
                                               uint2* __restrict__ out) {
    int base = blockIdx.x * 1024 + threadIdx.x;
    #pragma unroll
    for (int k = 0; k < 4; k++) {
        int i = base + k * 256;
        const float4* src;
        int off;
        if (i < 2097152)      { src = x;  off = 0; }
        else if (i < 2883584) { src = wa; off = 2097152; }
        else                  { src = wp; off = 2883584; }
        float4 v = src[i - off];
        uint2 o;
        o.x = (unsigned)f2bf(v.x) | ((unsigned)f2bf(v.y) << 16);
        o.y = (unsigned)f2bf(v.z) | ((unsigned)f2bf(v.w) << 16);
        out[i] = o;
    }
}

// ---------------------------------------------------------------------------
// GEMM core (proven), C = A @ B^T. Block 256x128, 4 waves 2x2, wave tile
// 128x64 (acc[8][4]), BK=64, GLL16 staging, swizzled LDS (0 conflicts).
// ---------------------------------------------------------------------------
#define GEMM_CORE_BIG(A_, B_, Kc, M0_, N0_)                                    \
    __shared__ unsigned short As[256 * 64];   /* 32 KB */                      \
    __shared__ unsigned short Bs[128 * 64];   /* 16 KB */                      \
    const int tid = threadIdx.x;                                               \
    const int lane = tid & 63, wav = tid >> 6;                                 \
    const int r16 = lane & 15, quad = lane >> 4;                               \
    const int M0 = (M0_), N0 = (N0_);                                          \
    const int wm = wav >> 1, wn = wav & 1;                                     \
    const int m0 = M0 + wm * 128, n0 = N0 + wn * 64;                           \
    const int rr0 = tid >> 3;                                                  \
    const int cc0 = (tid - rr0) & 7;                                           \
    const unsigned short* pA0 = A_ + (size_t)(M0 + rr0) * Kc + cc0 * 8;        \
    const unsigned short* pB0 = B_ + (size_t)(N0 + rr0) * Kc + cc0 * 8;        \
    unsigned short* lA0 = As + (size_t)(wav * 64) * 8;                         \
    unsigned short* lB0 = Bs + (size_t)(wav * 64) * 8;                         \
    const int fa = wm * 128 + r16, fb = wn * 64 + r16;                         \
    const int swa0 = (quad + fa) & 7, swa1 = (swa0 + 4) & 7;                   \
    const int swb0 = (quad + fb) & 7, swb1 = (swb0 + 4) & 7;                   \
    floatx4 acc[8][4];                                                         \
    _Pragma("unroll") for (int i = 0; i < 8; i++)                              \
        _Pragma("unroll") for (int j = 0; j < 4; j++) acc[i][j] = (floatx4)0.0f; \
    _Pragma("unroll 1") for (int ks = 0; ks < (Kc / 64); ks++) {               \
        _Pragma("unroll") for (int p = 0; p < 8; p++)                          \
            GLL16(pA0 + (size_t)ks * 64 + (size_t)p * 32 * Kc,                 \
                  lA0 + (size_t)p * 2048);                                     \
        _Pragma("unroll") for (int p = 0; p < 4; p++)                          \
            GLL16(pB0 + (size_t)ks * 64 + (size_t)p * 32 * Kc,                 \
                  lB0 + (size_t)p * 2048);                                     \
        __syncthreads();                                                       \
        short8 af[8], bf[4];                                                   \
        _Pragma("unroll") for (int i = 0; i < 8; i++)                          \
            af[i] = *(const short8*)(As + (fa + i * 16) * 64 + swa0 * 8);      \
        _Pragma("unroll") for (int j = 0; j < 4; j++)                          \
            bf[j] = *(const short8*)(Bs + (fb + j * 16) * 64 + swb0 * 8);      \
        _Pragma("unroll") for (int i = 0; i < 8; i++)                          \
            _Pragma("unroll") for (int j = 0; j < 4; j++)                      \
                acc[i][j] = __builtin_amdgcn_mfma_f32_16x16x32_bf16(           \
                    af[i], bf[j], acc[i][j], 0, 0, 0);                         \
        _Pragma("unroll") for (int i = 0; i < 8; i++)                          \
            af[i] = *(const short8*)(As + (fa + i * 16) * 64 + swa1 * 8);      \
        _Pragma("unroll") for (int j = 0; j < 4; j++)                          \
            bf[j] = *(const short8*)(Bs + (fb + j * 16) * 64 + swb1 * 8);      \
        _Pragma("unroll") for (int i = 0; i < 8; i++)                          \
            _Pragma("unroll") for (int j = 0; j < 4; j++)                      \
                acc[i][j] = __builtin_amdgcn_mfma_f32_16x16x32_bf16(           \
                    af[i], bf[j], acc[i][j], 0, 0, 0);                         \
        __syncthreads();                                                       \
    }

// ---------------- GEMM1: qkv = xb @ Wab^T, fused norm+erf -> E --------------
// 1-D grid 768, XCD-bijective swizzle, 2 blocks/CU (register-bound: 212 regs).
// E layout: [three][b][h][t][hs], bf16 bits.
__global__ __launch_bounds__(256, 2) void gemm1_qkv_norm(const unsigned short* __restrict__ A,
                                                         const unsigned short* __restrict__ Bm,
                                                         unsigned short* __restrict__ E) {
    const int wg = blockIdx.x;                 // 0..767
    const int swz = (wg & 7) * 96 + (wg >> 3); // bijective, 768 % 8 == 0
    const int bx = swz % 24, by = swz / 24;
    GEMM_CORE_BIG(A, Bm, 1024, by * 256, bx * 128)

    // fused per-64-group normalization: this wave's 64-col tile == one (three,h)
    int gcol  = n0 >> 6;            // 0..47
    int three = gcol >> 4, h = gcol & 15;
    #pragma unroll
    for (int i = 0; i < 8; i++) {
        #pragma unroll
        for (int r = 0; r < 4; r++) {
            float s = 0.f, ss = 0.f;
            #pragma unroll
            for (int j = 0; j < 4; j++) { float v = acc[i][j][r]; s += v; ss += v * v; }
            s = sum16(s); ss = sum16(ss);
            float mean = s * (1.0f / 64.0f);
            float var  = (ss - s * s * (1.0f / 64.0f)) * (1.0f / 63.0f);  // ddof=1
            float rstd = rsqrtf(var);
            int rowm = m0 + i * 16 + quad * 4 + r;     // = b*2048 + t
            int bb = rowm >> 11, tt2 = rowm & 2047;
            size_t base = ((((size_t)three * 4 + bb) * 16 + h) * 2048 + tt2) * 64;
            #pragma unroll
            for (int j = 0; j < 4; j++) {
                float v = (acc[i][j][r] - mean) * rstd;
                if (three < 2) v = erf_fast(v);
                E[base + j * 16 + r16] = f2bf(v);
            }
        }
    }
}

// ---------------- GEMM2 v4: out = x + vt @ Wp^T (fp32 out), K-split ---------
// Block 128(M)x128(N), BK=128 supertile, 4 waves (wk = K-half, wn = N-half).
// Wave (wk,wn): 128x64 partial, acc[8][4] (proven intensity). 16-slot swizzle.
// Symmetric-exchange epilogue: wk=0 deposits rows 64..127 (fp32, LDS region
// R0), wk=1 deposits rows 0..63 (region R1); barrier; wk=0 reduces+writes
// rows 0..63, wk=1 rows 64..127 -> all 256 threads stream X/Out traffic.
// Out stores nontemporal (never re-read). One commutative-identical
// reassociation per element (same as R11).
__global__ __launch_bounds__(256, 2) void gemm2_proj_add(const unsigned short* __restrict__ A,
                                                         const unsigned short* __restrict__ Bm,
                                                         const float* __restrict__ X,
                                                         float* __restrict__ Out) {
    __shared__ unsigned short L[32768];        // 64 KB: A 32KB | B 32KB
    unsigned short* LB = L + 16384;
    const int wg = blockIdx.x;                 // 0..511
    const int swz = (wg & 7) * 64 + (wg >> 3); // bijective, 512 % 8 == 0
    const int bx = swz & 7, by = swz >> 3;
    const int tid = threadIdx.x;
    const int lane = tid & 63, wav = tid >> 6;
    const int r16 = lane & 15, quad = lane >> 4;
    const int M0 = by * 128, N0 = bx * 128;
    const int wk = wav >> 1, wn = wav & 1;
    const int n0 = N0 + wn * 64;
    const int rr = tid >> 4;                   // 0..15 (staged row within round)
    const int cc = ((tid & 15) - rr) & 15;     // staged chunk (16B granule)
    const unsigned short* pSA = A  + (size_t)(M0 + rr) * 1024 + cc * 8;
    const unsigned short* pSB = Bm + (size_t)(N0 + rr) * 1024 + cc * 8;
    unsigned short* lA0 = L  + wav * 512;      // wave-uniform + lane*16B
    unsigned short* lB0 = LB + wav * 512;
    const int slot = (wk * 8 + quad + r16) & 15;            // read slot, half0
    const int slot1 = (wk * 8 + quad + 4 + r16) & 15;       // half1

    floatx4 acc[8][4];
    #pragma unroll
    for (int i = 0; i < 8; i++)
        #pragma unroll
        for (int j = 0; j < 4; j++) acc[i][j] = (floatx4)0.0f;

    #pragma unroll 1
    for (int ks = 0; ks < 8; ks++) {           // 8 x BK=128 supertiles
        #pragma unroll
        for (int p = 0; p < 8; p++)            // A: 8 rounds x 16 rows
            GLL16(pSA + (size_t)ks * 128 + (size_t)p * 16 * 1024,
                  lA0 + (size_t)p * 2048);
        #pragma unroll
        for (int p = 0; p < 8; p++)            // B: 8 rounds x 16 rows
            GLL16(pSB + (size_t)ks * 128 + (size_t)p * 16 * 1024,
                  lB0 + (size_t)p * 2048);
        __syncthreads();
        short8 af[8], bf[4];
        #pragma unroll
        for (int i = 0; i < 8; i++)            // rows r16 + i*16 (0..127)
            af[i] = *(const short8*)(L + (r16 + i * 16) * 128 + slot * 8);
        #pragma unroll
        for (int j = 0; j < 4; j++)            // rows wn*64 + r16 + j*16
            bf[j] = *(const short8*)(LB + (wn * 64 + r16 + j * 16) * 128 + slot * 8);
        #pragma unroll
        for (int i = 0; i < 8; i++)
            #pragma unroll
            for (int j = 0; j < 4; j++)
                acc[i][j] = __builtin_amdgcn_mfma_f32_16x16x32_bf16(
                    af[i], bf[j], acc[i][j], 0, 0, 0);
        #pragma unroll
        for (int i = 0; i < 8; i++)
            af[i] = *(const short8*)(L + (r16 + i * 16) * 128 + slot1 * 8);
        #pragma unroll
        for (int j = 0; j < 4; j++)
            bf[j] = *(const short8*)(LB + (wn * 64 + r16 + j * 16) * 128 + slot1 * 8);
        #pragma unroll
        for (int i = 0; i < 8; i++)
            #pragma unroll
            for (int j = 0; j < 4; j++)
                acc[i][j] = __builtin_amdgcn_mfma_f32_16x16x32_bf16(
                    af[i], bf[j], acc[i][j], 0, 0, 0);
        __syncthreads();
    }

    // ---- symmetric exchange: each wave deposits the half it will NOT write.
    // R0 (floats 0..8191):  wk=0's rows 64..127 ; R1 (8192..16383): wk=1's 0..63
    float* Lf = (float*)L;                     // 16384 floats = 64 KB
    if (wk == 0) {
        #pragma unroll
        for (int i = 4; i < 8; i++)
            #pragma unroll
            for (int j = 0; j < 4; j++)
                #pragma unroll
                for (int r = 0; r < 4; r++)
                    Lf[wn * 4096 + ((i - 4) * 16 + quad * 4 + r) * 64 + j * 16 + r16] =
                        acc[i][j][r];
    } else {
        #pragma unroll
        for (int i = 0; i < 4; i++)
            #pragma unroll
            for (int j = 0; j < 4; j++)
                #pragma unroll
                for (int r = 0; r < 4; r++)
                    Lf[8192 + wn * 4096 + (i * 16 + quad * 4 + r) * 64 + j * 16 + r16] =
                        acc[i][j][r];
    }
    __syncthreads();
    if (wk == 0) {                             // reduce + write rows 0..63
        #pragma unroll
        for (int i = 0; i < 4; i++)
            #pragma unroll
            for (int j = 0; j < 4; j++)
                #pragma unroll
                for (int r = 0; r < 4; r++) {
                    int row = i * 16 + quad * 4 + r, col = j * 16 + r16;
                    float v = acc[i][j][r] + Lf[8192 + wn * 4096 + row * 64 + col];
                    size_t idx = (size_t)(M0 + row) * 1024 + n0 + col;
                    __builtin_nontemporal_store(v + X[idx], &Out[idx]);
                }
    } else {                                   // reduce + write rows 64..127
        #pragma unroll
        for (int i = 4; i < 8; i++)
            #pragma unroll
            for (int j = 0; j < 4; j++)
                #pragma unroll
                for (int r = 0; r < 4; r++) {
                    int row = i * 16 + quad * 4 + r, col = j * 16 + r16;
                    float v = acc[i][j][r] + Lf[wn * 4096 + (row - 64) * 64 + col];
                    size_t idx = (size_t)(M0 + row) * 1024 + n0 + col;
                    __builtin_nontemporal_store(v + X[idx], &Out[idx]);
                }
    }
}

// ---------------- rolling chunked scan -> vt --------------------------------
// Exact recursion carried in registers: sv_t = v_t - G_t * sv_{t-1},
//   G_t = k~_{t-1}.k_t ; vt_t[i] = H0 sv_t[i] + w_i H1 sv_{t-1}[i].
// One wave per (b,h,chunk-of-16): 64 x 128 = 8192 waves = 2048 blocks.
__global__ __launch_bounds__(256) void band_vt(const unsigned short* __restrict__ E,
                                               const float* __restrict__ w,
                                               const float* __restrict__ eta,
                                               unsigned short* __restrict__ vt) {
    const int lane = threadIdx.x & 63;
    const int wav  = threadIdx.x >> 6;
    const int gid  = blockIdx.x * 4 + wav;        // 0..8191
    const int chunk = gid & 127;                  // 128 chunks of 16 t
    const int p     = gid >> 7;                   // (b,h): 0..63
    const int b = p >> 4, h = p & 15;
    const int t0 = chunk * 16;

    const size_t PL = (size_t)4 * 16 * 2048 * 64;               // one "three" plane
    const size_t pbh = ((size_t)b * 16 + h) * (2048 * 64);
    const unsigned short* qb = E + pbh;
    const unsigned short* kb = E + PL + pbh;
    const unsigned short* vb = E + 2 * PL + pbh;

    const float e  = eta[h * 64 + lane];
    const float wi = w[h * 64 + lane];

    // ---- warm-up: rolling kh_{t0-1} and seeded sv_{t0-1} (wave-uniform guards)
    float kh_p, sv_p;
    if (t0 == 0) {
        kh_p = 0.f;
        sv_p = 0.f;
    } else {
        float k1 = bflo(kb[(size_t)(t0 - 1) * 64 + lane]);
        float k2 = bflo(kb[(size_t)(t0 - 2) * 64 + lane]);
        float k3 = bflo(kb[(size_t)(t0 - 3) * 64 + lane]);
        float v1 = bflo(vb[(size_t)(t0 - 1) * 64 + lane]);
        float v2 = bflo(vb[(size_t)(t0 - 2) * 64 + lane]);
        float v3 = bflo(vb[(size_t)(t0 - 3) * 64 + lane]);
        float G1 = sum64_all((k2 * e) * k1);      // G_{t0-1} = k~_{t0-2}.k_{t0-1}
        float G2 = sum64_all((k3 * e) * k2);      // G_{t0-2} = k~_{t0-3}.k_{t0-2}
        sv_p = v1 - G1 * (v2 - G2 * v3);          // sv_{t0-1}, 3-term seed
        kh_p = k1 * e;
    }

    const unsigned short* pq = qb + (size_t)t0 * 64 + lane;
    const unsigned short* pk = kb + (size_t)t0 * 64 + lane;
    const unsigned short* pv = vb + (size_t)t0 * 64 + lane;
    unsigned short* po = vt + ((size_t)b * 2048 + t0) * 1024 + h * 64 + lane;

    #pragma unroll
    for (int tt = 0; tt < 16; tt++) {
        float qt = bflo(pq[tt * 64]);
        float kt = bflo(pk[tt * 64]);
        float vv = bflo(pv[tt * 64]);
        float kh = kt * e;
        float Gt = sum64_all(kh_p * kt);          // k~_{t-1}.k_t
        float H0 = sum64_all(kh * qt);            // k~_t.q_t
        float H1 = sum64_all(kh_p * qt);          // k~_{t-1}.q_t
        float sv = fmaf(-Gt, sv_p, vv);           // sv_t = v_t - G_t sv_{t-1}
        float r  = fmaf(H0, sv, wi * (H1 * sv_p));
        po[(size_t)tt * 1024] = f2bf(r);
        kh_p = kh;
        sv_p = sv;
    }
}

// ---------------------------------------------------------------------------
extern "C" void kernel_launch(void* const* d_in, const int* in_sizes, int n_in,
                              void* d_out, int out_size, void* d_ws, size_t ws_size,
                              hipStream_t stream) {
    const float* x   = (const float*)d_in[0];   // (4,2048,1024)
    const float* Wa  = (const float*)d_in[1];   // (3072,1024)
    const float* Wp  = (const float*)d_in[2];   // (1024,1024)
    const float* w   = (const float*)d_in[3];   // (1024,)
    const float* eta = (const float*)d_in[4];   // (1024,)
    float* out = (float*)d_out;

    char* ws = (char*)d_ws;
    unsigned short* xb  = (unsigned short*)(ws + 0);          // 16777216 B
    unsigned short* Wab = (unsigned short*)(ws + 16777216);   //  6291456 B
    unsigned short* Wpb = (unsigned short*)(ws + 23068672);   //  2097152 B
    unsigned short* E   = (unsigned short*)(ws + 25165824);   // 50331648 B
    unsigned short* vtb = (unsigned short*)(ws + 75497728);   // 16777216 B  -> end 92274944

    castall<<<3072, 256, 0, stream>>>((const float4*)x, (const float4*)Wa,
                                      (const float4*)Wp, (uint2*)xb);

    gemm1_qkv_norm<<<768, 256, 0, stream>>>(xb, Wab, E);
    band_vt<<<2048, 256, 0, stream>>>(E, w, eta, vtb);
    gemm2_proj_add<<<512, 256, 0, stream>>>(vtb, Wpb, x, out);
}

// Round 13
// 196.788 us; speedup vs baseline: 1.0374x; 1.0374x over previous
//
#include <hip/hip_runtime.h>
#include <math.h>

// ---------------------------------------------------------------------------
// RWKV7-ish CausalSelfAttention, MI355X gfx950.
// B=4 T=2048 C=1024 NH=16 HS=64.
// Pipeline: castall v2 (ILP-4) -> bf16 ;
//   GEMM1: proven 4-wave 256x128 core (128x64 wave tiles, BK=64, GLL16 +
//          swizzled LDS, 2-barrier, XCD swizzle) + fused groupnorm/erf -> E ;
//   band_vt rolling chunked scan -> vt ;
//   GEMM2 v3: 128x128 block, 4 waves K-SPLIT (wk,wn): each wave a 128x64
//          PARTIAL over half of each BK=128 supertile (acc[8][4] = gemm1's
//          proven intensity), 16-slot swizzle, 64KB LDS, LDS fp32 reduction
//          epilogue + residual. Grid 512 = 2 blk/CU.
// R12 lesson: symmetric-exchange epilogue + nontemporal stores regressed
//   (+9.5us) -- R11's asymmetric reduce lets wk=1 waves retire early and
//   keeps stores in the L2 write-combine path. This file == R11 verbatim
//   (best measured: 194.7us).
// Ceiling ledger: gemm1 = 67us register-capped (212 regs/wave -> 2
//   waves/SIMD); 4 schedule rewrites + 2 occupancy pushes regressed/null.
// Workspace: xb 16MB | Wab 6MB | Wpb 2MB | E 48MB | vt 16MB = 88MiB
// ---------------------------------------------------------------------------

typedef __attribute__((ext_vector_type(8))) short short8;     // 8 x bf16 bits
typedef __attribute__((ext_vector_type(4))) float floatx4;

#define GLL16(g, l)                                                            \
    __builtin_amdgcn_global_load_lds(                                          \
        (const __attribute__((address_space(1))) void*)(g),                    \
        (__attribute__((address_space(3))) void*)(l), 16, 0, 0)

static __device__ __forceinline__ unsigned short f2bf(float f) {
    unsigned u = __float_as_uint(f);
    unsigned r = (u + 0x7fffu + ((u >> 16) & 1u)) >> 16;
    return (unsigned short)r;
}
static __device__ __forceinline__ float bflo(unsigned v) { return __uint_as_float(v << 16); }

// Abramowitz-Stegun 7.1.28: |err| <= 3e-7, branch-free.
static __device__ __forceinline__ float erf_fast(float x) {
    float ax = __builtin_fabsf(x);
    float p = fmaf(0.0000430638f, ax, 0.0002765672f);
    p = fmaf(p, ax, 0.0001520143f);
    p = fmaf(p, ax, 0.0092705272f);
    p = fmaf(p, ax, 0.0422820123f);
    p = fmaf(p, ax, 0.0705230784f);
    p = fmaf(p, ax, 1.0f);
    float r = 1.0f / p;
    float r2 = r * r, r4 = r2 * r2, r8 = r4 * r4, r16 = r8 * r8;
    return __builtin_copysignf(1.0f - r16, x);
}

// sum across the 16 lanes of a DPP row, result in every lane of the row.
static __device__ __forceinline__ float sum16(float x) {
    int t;
    t = __builtin_amdgcn_update_dpp(0, __float_as_int(x), 0x128, 0xf, 0xf, false); // row_ror:8
    x += __int_as_float(t);
    t = __builtin_amdgcn_update_dpp(0, __float_as_int(x), 0x124, 0xf, 0xf, false); // row_ror:4
    x += __int_as_float(t);
    t = __builtin_amdgcn_update_dpp(0, __float_as_int(x), 0x122, 0xf, 0xf, false); // row_ror:2
    x += __int_as_float(t);
    t = __builtin_amdgcn_update_dpp(0, __float_as_int(x), 0x121, 0xf, 0xf, false); // row_ror:1
    x += __int_as_float(t);
    return x;
}
// full 64-lane sum, result in every lane.
static __device__ __forceinline__ float sum64_all(float x) {
    x = sum16(x);
    int t = __builtin_amdgcn_ds_swizzle(__float_as_int(x), 0x401F);  // xor 16 (within 32)
    x += __int_as_float(t);
    x += __shfl_xor(x, 32, 64);                                      // xor 32
    return x;
}

// ---------------- fused cast fp32 -> bf16 (x | Wa | Wp, contiguous out) -----
__global__ __launch_bounds__(256) void castall(const float4* __restrict__ x,
                                               const float4* __restrict__ wa,
                                               const float4* __restrict__ wp,
                                               uint2* __restrict__ out) {
    int base = blockIdx.x * 1024 + threadIdx.x;
    #pragma unroll
    for (int k = 0; k < 4; k++) {
        int i = base + k * 256;
        const float4* src;
        int off;
        if (i < 2097152)      { src = x;  off = 0; }
        else if (i < 2883584) { src = wa; off = 2097152; }
        else                  { src = wp; off = 2883584; }
        float4 v = src[i - off];
        uint2 o;
        o.x = (unsigned)f2bf(v.x) | ((unsigned)f2bf(v.y) << 16);
        o.y = (unsigned)f2bf(v.z) | ((unsigned)f2bf(v.w) << 16);
        out[i] = o;
    }
}

// ---------------------------------------------------------------------------
// GEMM core (proven), C = A @ B^T. Block 256x128, 4 waves 2x2, wave tile
// 128x64 (acc[8][4]), BK=64, GLL16 staging, swizzled LDS (0 conflicts).
// ---------------------------------------------------------------------------
#define GEMM_CORE_BIG(A_, B_, Kc, M0_, N0_)                                    \
    __shared__ unsigned short As[256 * 64];   /* 32 KB */                      \
    __shared__ unsigned short Bs[128 * 64];   /* 16 KB */                      \
    const int tid = threadIdx.x;                                               \
    const int lane = tid & 63, wav = tid >> 6;                                 \
    const int r16 = lane & 15, quad = lane >> 4;                               \
    const int M0 = (M0_), N0 = (N0_);                                          \
    const int wm = wav >> 1, wn = wav & 1;                                     \
    const int m0 = M0 + wm * 128, n0 = N0 + wn * 64;                           \
    const int rr0 = tid >> 3;                                                  \
    const int cc0 = (tid - rr0) & 7;                                           \
    const unsigned short* pA0 = A_ + (size_t)(M0 + rr0) * Kc + cc0 * 8;        \
    const unsigned short* pB0 = B_ + (size_t)(N0 + rr0) * Kc + cc0 * 8;        \
    unsigned short* lA0 = As + (size_t)(wav * 64) * 8;                         \
    unsigned short* lB0 = Bs + (size_t)(wav * 64) * 8;                         \
    const int fa = wm * 128 + r16, fb = wn * 64 + r16;                         \
    const int swa0 = (quad + fa) & 7, swa1 = (swa0 + 4) & 7;                   \
    const int swb0 = (quad + fb) & 7, swb1 = (swb0 + 4) & 7;                   \
    floatx4 acc[8][4];                                                         \
    _Pragma("unroll") for (int i = 0; i < 8; i++)                              \
        _Pragma("unroll") for (int j = 0; j < 4; j++) acc[i][j] = (floatx4)0.0f; \
    _Pragma("unroll 1") for (int ks = 0; ks < (Kc / 64); ks++) {               \
        _Pragma("unroll") for (int p = 0; p < 8; p++)                          \
            GLL16(pA0 + (size_t)ks * 64 + (size_t)p * 32 * Kc,                 \
                  lA0 + (size_t)p * 2048);                                     \
        _Pragma("unroll") for (int p = 0; p < 4; p++)                          \
            GLL16(pB0 + (size_t)ks * 64 + (size_t)p * 32 * Kc,                 \
                  lB0 + (size_t)p * 2048);                                     \
        __syncthreads();                                                       \
        short8 af[8], bf[4];                                                   \
        _Pragma("unroll") for (int i = 0; i < 8; i++)                          \
            af[i] = *(const short8*)(As + (fa + i * 16) * 64 + swa0 * 8);      \
        _Pragma("unroll") for (int j = 0; j < 4; j++)                          \
            bf[j] = *(const short8*)(Bs + (fb + j * 16) * 64 + swb0 * 8);      \
        _Pragma("unroll") for (int i = 0; i < 8; i++)                          \
            _Pragma("unroll") for (int j = 0; j < 4; j++)                      \
                acc[i][j] = __builtin_amdgcn_mfma_f32_16x16x32_bf16(           \
                    af[i], bf[j], acc[i][j], 0, 0, 0);                         \
        _Pragma("unroll") for (int i = 0; i < 8; i++)                          \
            af[i] = *(const short8*)(As + (fa + i * 16) * 64 + swa1 * 8);      \
        _Pragma("unroll") for (int j = 0; j < 4; j++)                          \
            bf[j] = *(const short8*)(Bs + (fb + j * 16) * 64 + swb1 * 8);      \
        _Pragma("unroll") for (int i = 0; i < 8; i++)                          \
            _Pragma("unroll") for (int j = 0; j < 4; j++)                      \
                acc[i][j] = __builtin_amdgcn_mfma_f32_16x16x32_bf16(           \
                    af[i], bf[j], acc[i][j], 0, 0, 0);                         \
        __syncthreads();                                                       \
    }

// ---------------- GEMM1: qkv = xb @ Wab^T, fused norm+erf -> E --------------
// 1-D grid 768, XCD-bijective swizzle, 2 blocks/CU (register-bound: 212 regs).
// E layout: [three][b][h][t][hs], bf16 bits.
__global__ __launch_bounds__(256, 2) void gemm1_qkv_norm(const unsigned short* __restrict__ A,
                                                         const unsigned short* __restrict__ Bm,
                                                         unsigned short* __restrict__ E) {
    const int wg = blockIdx.x;                 // 0..767
    const int swz = (wg & 7) * 96 + (wg >> 3); // bijective, 768 % 8 == 0
    const int bx = swz % 24, by = swz / 24;
    GEMM_CORE_BIG(A, Bm, 1024, by * 256, bx * 128)

    // fused per-64-group normalization: this wave's 64-col tile == one (three,h)
    int gcol  = n0 >> 6;            // 0..47
    int three = gcol >> 4, h = gcol & 15;
    #pragma unroll
    for (int i = 0; i < 8; i++) {
        #pragma unroll
        for (int r = 0; r < 4; r++) {
            float s = 0.f, ss = 0.f;
            #pragma unroll
            for (int j = 0; j < 4; j++) { float v = acc[i][j][r]; s += v; ss += v * v; }
            s = sum16(s); ss = sum16(ss);
            float mean = s * (1.0f / 64.0f);
            float var  = (ss - s * s * (1.0f / 64.0f)) * (1.0f / 63.0f);  // ddof=1
            float rstd = rsqrtf(var);
            int rowm = m0 + i * 16 + quad * 4 + r;     // = b*2048 + t
            int bb = rowm >> 11, tt2 = rowm & 2047;
            size_t base = ((((size_t)three * 4 + bb) * 16 + h) * 2048 + tt2) * 64;
            #pragma unroll
            for (int j = 0; j < 4; j++) {
                float v = (acc[i][j][r] - mean) * rstd;
                if (three < 2) v = erf_fast(v);
                E[base + j * 16 + r16] = f2bf(v);
            }
        }
    }
}

// ---------------- GEMM2 v3: out = x + vt @ Wp^T (fp32 out), K-split ---------
// Block 128(M)x128(N), BK=128 supertile, 4 waves (wk = K-half, wn = N-half).
// Wave (wk,wn): 128x64 partial over chunks [wk*8, wk*8+8) of each supertile,
// acc[8][4] -- gemm1's proven intensity. 16-slot swizzle: granule (row r,
// chunk c) at slot (c+r)&15; staging linear in tid (rr=tid>>4, cc=
// ((tid&15)-rr)&15); read slot (wk*8+quad+r16)&15 recovers chunk wk*8+quad
// (+4 for half1) -> sequential K within wave. Epilogue: wk=1 stores fp32
// partial to LDS (64KB reuse), wk=0 adds + X residual. One reassociation.
__global__ __launch_bounds__(256, 2) void gemm2_proj_add(const unsigned short* __restrict__ A,
                                                         const unsigned short* __restrict__ Bm,
                                                         const float* __restrict__ X,
                                                         float* __restrict__ Out) {
    __shared__ unsigned short L[32768];        // 64 KB: A 32KB | B 32KB
    unsigned short* LB = L + 16384;
    const int wg = blockIdx.x;                 // 0..511
    const int swz = (wg & 7) * 64 + (wg >> 3); // bijective, 512 % 8 == 0
    const int bx = swz & 7, by = swz >> 3;
    const int tid = threadIdx.x;
    const int lane = tid & 63, wav = tid >> 6;
    const int r16 = lane & 15, quad = lane >> 4;
    const int M0 = by * 128, N0 = bx * 128;
    const int wk = wav >> 1, wn = wav & 1;
    const int n0 = N0 + wn * 64;
    const int rr = tid >> 4;                   // 0..15 (staged row within round)
    const int cc = ((tid & 15) - rr) & 15;     // staged chunk (16B granule)
    const unsigned short* pSA = A  + (size_t)(M0 + rr) * 1024 + cc * 8;
    const unsigned short* pSB = Bm + (size_t)(N0 + rr) * 1024 + cc * 8;
    unsigned short* lA0 = L  + wav * 512;      // wave-uniform + lane*16B
    unsigned short* lB0 = LB + wav * 512;
    const int slot = (wk * 8 + quad + r16) & 15;            // read slot, half0
    const int slot1 = (wk * 8 + quad + 4 + r16) & 15;       // half1

    floatx4 acc[8][4];
    #pragma unroll
    for (int i = 0; i < 8; i++)
        #pragma unroll
        for (int j = 0; j < 4; j++) acc[i][j] = (floatx4)0.0f;

    #pragma unroll 1
    for (int ks = 0; ks < 8; ks++) {           // 8 x BK=128 supertiles
        #pragma unroll
        for (int p = 0; p < 8; p++)            // A: 8 rounds x 16 rows
            GLL16(pSA + (size_t)ks * 128 + (size_t)p * 16 * 1024,
                  lA0 + (size_t)p * 2048);
        #pragma unroll
        for (int p = 0; p < 8; p++)            // B: 8 rounds x 16 rows
            GLL16(pSB + (size_t)ks * 128 + (size_t)p * 16 * 1024,
                  lB0 + (size_t)p * 2048);
        __syncthreads();
        short8 af[8], bf[4];
        #pragma unroll
        for (int i = 0; i < 8; i++)            // rows r16 + i*16 (0..127)
            af[i] = *(const short8*)(L + (r16 + i * 16) * 128 + slot * 8);
        #pragma unroll
        for (int j = 0; j < 4; j++)            // rows wn*64 + r16 + j*16
            bf[j] = *(const short8*)(LB + (wn * 64 + r16 + j * 16) * 128 + slot * 8);
        #pragma unroll
        for (int i = 0; i < 8; i++)
            #pragma unroll
            for (int j = 0; j < 4; j++)
                acc[i][j] = __builtin_amdgcn_mfma_f32_16x16x32_bf16(
                    af[i], bf[j], acc[i][j], 0, 0, 0);
        #pragma unroll
        for (int i = 0; i < 8; i++)
            af[i] = *(const short8*)(L + (r16 + i * 16) * 128 + slot1 * 8);
        #pragma unroll
        for (int j = 0; j < 4; j++)
            bf[j] = *(const short8*)(LB + (wn * 64 + r16 + j * 16) * 128 + slot1 * 8);
        #pragma unroll
        for (int i = 0; i < 8; i++)
            #pragma unroll
            for (int j = 0; j < 4; j++)
                acc[i][j] = __builtin_amdgcn_mfma_f32_16x16x32_bf16(
                    af[i], bf[j], acc[i][j], 0, 0, 0);
        __syncthreads();
    }

    // ---- K-split reduction: wk=1 partial -> LDS (fp32), wk=0 adds + residual
    float* Lf = (float*)L;                     // 16384 floats = 64 KB
    if (wk == 1) {
        #pragma unroll
        for (int i = 0; i < 8; i++)
            #pragma unroll
            for (int j = 0; j < 4; j++)
                #pragma unroll
                for (int r = 0; r < 4; r++)
                    Lf[wn * 8192 + (i * 16 + quad * 4 + r) * 64 + j * 16 + r16] =
                        acc[i][j][r];
    }
    __syncthreads();
    if (wk == 0) {
        #pragma unroll
        for (int i = 0; i < 8; i++)
            #pragma unroll
            for (int j = 0; j < 4; j++)
                #pragma unroll
                for (int r = 0; r < 4; r++) {
                    int row = i * 16 + quad * 4 + r, col = j * 16 + r16;
                    float v = acc[i][j][r] + Lf[wn * 8192 + row * 64 + col];
                    size_t idx = (size_t)(M0 + row) * 1024 + n0 + col;
                    Out[idx] = v + X[idx];
                }
    }
}

// ---------------- rolling chunked scan -> vt --------------------------------
// Exact recursion carried in registers: sv_t = v_t - G_t * sv_{t-1},
//   G_t = k~_{t-1}.k_t ; vt_t[i] = H0 sv_t[i] + w_i H1 sv_{t-1}[i].
// One wave per (b,h,chunk-of-16): 64 x 128 = 8192 waves = 2048 blocks.
__global__ __launch_bounds__(256) void band_vt(const unsigned short* __restrict__ E,
                                               const float* __restrict__ w,
                                               const float* __restrict__ eta,
                                               unsigned short* __restrict__ vt) {
    const int lane = threadIdx.x & 63;
    const int wav  = threadIdx.x >> 6;
    const int gid  = blockIdx.x * 4 + wav;        // 0..8191
    const int chunk = gid & 127;                  // 128 chunks of 16 t
    const int p     = gid >> 7;                   // (b,h): 0..63
    const int b = p >> 4, h = p & 15;
    const int t0 = chunk * 16;

    const size_t PL = (size_t)4 * 16 * 2048 * 64;               // one "three" plane
    const size_t pbh = ((size_t)b * 16 + h) * (2048 * 64);
    const unsigned short* qb = E + pbh;
    const unsigned short* kb = E + PL + pbh;
    const unsigned short* vb = E + 2 * PL + pbh;

    const float e  = eta[h * 64 + lane];
    const float wi = w[h * 64 + lane];

    // ---- warm-up: rolling kh_{t0-1} and seeded sv_{t0-1} (wave-uniform guards)
    float kh_p, sv_p;
    if (t0 == 0) {
        kh_p = 0.f;
        sv_p = 0.f;
    } else {
        float k1 = bflo(kb[(size_t)(t0 - 1) * 64 + lane]);
        float k2 = bflo(kb[(size_t)(t0 - 2) * 64 + lane]);
        float k3 = bflo(kb[(size_t)(t0 - 3) * 64 + lane]);
        float v1 = bflo(vb[(size_t)(t0 - 1) * 64 + lane]);
        float v2 = bflo(vb[(size_t)(t0 - 2) * 64 + lane]);
        float v3 = bflo(vb[(size_t)(t0 - 3) * 64 + lane]);
        float G1 = sum64_all((k2 * e) * k1);      // G_{t0-1} = k~_{t0-2}.k_{t0-1}
        float G2 = sum64_all((k3 * e) * k2);      // G_{t0-2} = k~_{t0-3}.k_{t0-2}
        sv_p = v1 - G1 * (v2 - G2 * v3);          // sv_{t0-1}, 3-term seed
        kh_p = k1 * e;
    }

    const unsigned short* pq = qb + (size_t)t0 * 64 + lane;
    const unsigned short* pk = kb + (size_t)t0 * 64 + lane;
    const unsigned short* pv = vb + (size_t)t0 * 64 + lane;
    unsigned short* po = vt + ((size_t)b * 2048 + t0) * 1024 + h * 64 + lane;

    #pragma unroll
    for (int tt = 0; tt < 16; tt++) {
        float qt = bflo(pq[tt * 64]);
        float kt = bflo(pk[tt * 64]);
        float vv = bflo(pv[tt * 64]);
        float kh = kt * e;
        float Gt = sum64_all(kh_p * kt);          // k~_{t-1}.k_t
        float H0 = sum64_all(kh * qt);            // k~_t.q_t
        float H1 = sum64_all(kh_p * qt);          // k~_{t-1}.q_t
        float sv = fmaf(-Gt, sv_p, vv);           // sv_t = v_t - G_t sv_{t-1}
        float r  = fmaf(H0, sv, wi * (H1 * sv_p));
        po[(size_t)tt * 1024] = f2bf(r);
        kh_p = kh;
        sv_p = sv;
    }
}

// ---------------------------------------------------------------------------
extern "C" void kernel_launch(void* const* d_in, const int* in_sizes, int n_in,
                              void* d_out, int out_size, void* d_ws, size_t ws_size,
                              hipStream_t stream) {
    const float* x   = (const float*)d_in[0];   // (4,2048,1024)
    const float* Wa  = (const float*)d_in[1];   // (3072,1024)
    const float* Wp  = (const float*)d_in[2];   // (1024,1024)
    const float* w   = (const float*)d_in[3];   // (1024,)
    const float* eta = (const float*)d_in[4];   // (1024,)
    float* out = (float*)d_out;

    char* ws = (char*)d_ws;
    unsigned short* xb  = (unsigned short*)(ws + 0);          // 16777216 B
    unsigned short* Wab = (unsigned short*)(ws + 16777216);   //  6291456 B
    unsigned short* Wpb = (unsigned short*)(ws + 23068672);   //  2097152 B
    unsigned short* E   = (unsigned short*)(ws + 25165824);   // 50331648 B
    unsigned short* vtb = (unsigned short*)(ws + 75497728);   // 16777216 B  -> end 92274944

    castall<<<3072, 256, 0, stream>>>((const float4*)x, (const float4*)Wa,
                                      (const float4*)Wp, (uint2*)xb);

    gemm1_qkv_norm<<<768, 256, 0, stream>>>(xb, Wab, E);
    band_vt<<<2048, 256, 0, stream>>>(E, w, eta, vtb);
    gemm2_proj_add<<<512, 256, 0, stream>>>(vtb, Wpb, x, out);
}